// Round 6
// baseline (132.293 us; speedup 1.0000x reference)
//
#include <hip/hip_runtime.h>
#include <hip/hip_bf16.h>
#include <stdint.h>

#define EMB 1024
#define NB 8
#define SEQ 2048
#define RANK 8
#define PS 72      // attn P LDS row stride (bf16 elems)
#define SPLIT 4    // KV splits in flash attention

typedef __attribute__((ext_vector_type(8))) short bf16x8;
typedef __attribute__((ext_vector_type(4))) float f32x4;
typedef unsigned short u16;
typedef unsigned int u32;

__device__ __forceinline__ u16 f2bf(float f) {
  u32 u = __builtin_bit_cast(u32, f);
  u = (u + 0x7fffu + ((u >> 16) & 1u)) >> 16;   // RNE
  return (u16)u;
}
__device__ __forceinline__ u32 pack2bf(float lo, float hi) {
  return (u32)f2bf(lo) | ((u32)f2bf(hi) << 16);
}
__device__ __forceinline__ void gll16(const void* g, void* l) {
  __builtin_amdgcn_global_load_lds(
      (const __attribute__((address_space(1))) unsigned int*)g,
      (__attribute__((address_space(3))) unsigned int*)l, 16, 0, 0);
}

// ---------------- fold: Weff[m][e] = W[h][e] + 2*sum_r B[h][r]*A[r][e]
__global__ __launch_bounds__(256) void fold_k(
    const float* __restrict__ Wq, const float* __restrict__ Wk, const float* __restrict__ Wv,
    const float* __restrict__ Aq, const float* __restrict__ Bq,
    const float* __restrict__ Ak, const float* __restrict__ Bk,
    const float* __restrict__ Av, const float* __restrict__ Bv,
    u16* __restrict__ weff) {
  int m = blockIdx.x;
  int mat = m >> 6, h = m & 63;
  const float* W = mat == 0 ? Wq : (mat == 1 ? Wk : Wv);
  const float* A = mat == 0 ? Aq : (mat == 1 ? Ak : Av);
  const float* B = mat == 0 ? Bq : (mat == 1 ? Bk : Bv);
  float bb[RANK];
#pragma unroll
  for (int r = 0; r < RANK; r++) bb[r] = 2.0f * B[h * RANK + r];
  int e = threadIdx.x * 4;
  float4 w4 = *(const float4*)(W + h * EMB + e);
  float a0 = w4.x, a1 = w4.y, a2 = w4.z, a3 = w4.w;
#pragma unroll
  for (int r = 0; r < RANK; r++) {
    float4 av = *(const float4*)(A + r * EMB + e);
    a0 += bb[r] * av.x; a1 += bb[r] * av.y; a2 += bb[r] * av.z; a3 += bb[r] * av.w;
  }
  u16* o = weff + (size_t)m * EMB + e;
  o[0] = f2bf(a0); o[1] = f2bf(a1); o[2] = f2bf(a2); o[3] = f2bf(a3);
}

// ---------------- projection GEMM: C[16384,192] = X * Weff^T
// 512 blocks x 512 threads (8 waves: 2 rowgrp x 4 colgrp), 32 rows/block.
// X staged fp32 via global_load_lds (16B) into 2x16KB double-buffered LDS in a
// column-chunk layout (source-permuted, dest linear). One barrier per k128
// stage. W streamed from L2 inside the compute loop.
__global__ __launch_bounds__(512) void proj_k(
    const float* __restrict__ X, const u16* __restrict__ weff,
    u16* __restrict__ qws, u16* __restrict__ kws, u16* __restrict__ vws) {
  __shared__ __align__(16) float xs[2][4096];   // 2 x 16KB

  int t = threadIdx.x;
  int w = t >> 6;                // 0..7
  int l = t & 63;
  int l15 = l & 15, lh = l >> 4;
  int rowgrp = w >> 2, colgrp = w & 3;
  int rbase = blockIdx.x * 32;

  // staging: wave w stages c16 = w*4 + (l>>4), row = (l&15)  (+16 for h=1)
  // LDS byte (within 16KB buf) = h*8192 + c16*256 + row*16 == h*8192 + w*1024 + l*16
  const float* gsrc0 = X + (size_t)(rbase + l15) * EMB + (w * 4 + lh) * 4;
  const float* gsrc1 = gsrc0 + (size_t)16 * EMB;
  char* lb = (char*)&xs[0][0] + w * 1024;

  const u16* wp[3];
#pragma unroll
  for (int tt = 0; tt < 3; tt++)
    wp[tt] = weff + (size_t)(colgrp * 48 + tt * 16 + l15) * EMB + lh * 8;

  f32x4 acc[3];
  f32x4 zero = {0.f, 0.f, 0.f, 0.f};
#pragma unroll
  for (int tt = 0; tt < 3; tt++) acc[tt] = zero;

  int rdbase = rowgrp * 8192 + l15 * 16;   // byte offset in buffer

  // prologue: stage k=0 into buf0
  gll16(gsrc0, lb);
  gll16(gsrc1, lb + 8192);
  __syncthreads();

  int cur = 0;
  for (int k0 = 0; k0 < EMB; k0 += 128) {
    if (k0 + 128 < EMB) {
      gll16(gsrc0 + k0 + 128, lb + (cur ^ 1) * 16384);
      gll16(gsrc1 + k0 + 128, lb + (cur ^ 1) * 16384 + 8192);
    }
    const char* xb = (const char*)xs + cur * 16384 + rdbase;
#pragma unroll
    for (int j = 0; j < 4; j++) {
      int c0 = (j * 8 + lh * 2) * 256;
      f32x4 lo = *(const f32x4*)(xb + c0);
      f32x4 hi = *(const f32x4*)(xb + c0 + 256);
      union { bf16x8 v; u32 u[4]; } au;
      au.u[0] = pack2bf(lo.x, lo.y); au.u[1] = pack2bf(lo.z, lo.w);
      au.u[2] = pack2bf(hi.x, hi.y); au.u[3] = pack2bf(hi.z, hi.w);
#pragma unroll
      for (int tt = 0; tt < 3; tt++) {
        bf16x8 wf = *(const bf16x8*)(wp[tt] + k0 + j * 32);
        acc[tt] = __builtin_amdgcn_mfma_f32_16x16x32_bf16(au.v, wf, acc[tt], 0, 0, 0);
      }
    }
    __syncthreads();
    cur ^= 1;
  }

  // ---- epilogue: scatter to q (x0.125 folded) / k / v^T (bf16)
#pragma unroll
  for (int tt = 0; tt < 3; tt++) {
    int c = colgrp * 48 + tt * 16 + l15;
#pragma unroll
    for (int r = 0; r < 4; r++) {
      int rr = rbase + rowgrp * 16 + lh * 4 + r;
      float av = acc[tt][r];
      if (c < 64) av *= 0.125f;                 // fold softmax scale into q
      u16 v = f2bf(av);
      if (c < 64) {
        qws[(size_t)rr * 64 + c] = v;
      } else if (c < 128) {
        kws[(size_t)rr * 64 + (c - 64)] = v;
      } else {
        int bb = rr >> 11, tok = rr & 2047;
        vws[((size_t)(bb * 64 + (c - 128))) * SEQ + tok] = v;
      }
    }
  }
}

// ---------------- flash attention, KV-split: grid (32 qtiles, 8 batch, SPLIT).
// Swapped QK^T (mfma(K,Q)): lane l15 = q-row, holds 16 key-scores in regs.
// Softmax: in-lane tree + 2 shfl_xor. K/V/mask direct from global (L2-hot),
// no staging, no barriers. Only P goes through per-wave LDS. Defer-max (THR=8).
__global__ __launch_bounds__(256) void attn_k(
    const u16* __restrict__ qws, const u16* __restrict__ kws, const u16* __restrict__ vws,
    const int* __restrict__ mrk,
    float* __restrict__ po, float* __restrict__ pmp, float* __restrict__ plp) {
  __shared__ __align__(16) u16 ps[4][16 * PS];

  int b = blockIdx.y;
  int z = blockIdx.z;
  int q0 = blockIdx.x * 64;
  int w = threadIdx.x >> 6;
  int l = threadIdx.x & 63;
  int l15 = l & 15, lh = l >> 4;

  const u16* qp = qws + ((size_t)(b * SEQ + q0 + w * 16 + l15)) * 64 + lh * 8;
  bf16x8 qb0 = *(const bf16x8*)qp;
  bf16x8 qb1 = *(const bf16x8*)(qp + 32);

  f32x4 o[4];
  f32x4 zero = {0.f, 0.f, 0.f, 0.f};
#pragma unroll
  for (int ht = 0; ht < 4; ht++) o[ht] = zero;
  float mrow = -30000.0f, lrow = 0.f;

  u16* pw = &ps[w][0];
  int pwr = l15 * PS;

  for (int kc = 0; kc < SEQ / 64 / SPLIT; kc++) {
    int kk = z * (SEQ / SPLIT) + kc * 64;

    // ---- burst: K frags (A-op), mask, V frags (B-op) — all independent
    bf16x8 ka[4][2];
#pragma unroll
    for (int nt = 0; nt < 4; nt++) {
      const u16* kp = kws + ((size_t)(b * SEQ + kk + nt * 16 + l15)) * 64 + lh * 8;
      ka[nt][0] = *(const bf16x8*)kp;
      ka[nt][1] = *(const bf16x8*)(kp + 32);
    }
    int4 mi[4];
#pragma unroll
    for (int nt = 0; nt < 4; nt++)
      mi[nt] = *(const int4*)(mrk + b * SEQ + kk + nt * 16 + lh * 4);
    bf16x8 vb[4][2];
#pragma unroll
    for (int ht = 0; ht < 4; ht++) {
      const u16* vp = vws + ((size_t)(b * 64 + ht * 16 + l15)) * SEQ + kk + lh * 8;
      vb[ht][0] = *(const bf16x8*)vp;
      vb[ht][1] = *(const bf16x8*)(vp + 32);
    }

    // ---- S^T = K Q^T : lane(l15=q-row) reg r of sa[nt] = score(key nt*16+lh*4+r)
    f32x4 sa[4];
#pragma unroll
    for (int nt = 0; nt < 4; nt++) {
      f32x4 s = zero;
      s = __builtin_amdgcn_mfma_f32_16x16x32_bf16(ka[nt][0], qb0, s, 0, 0, 0);
      s = __builtin_amdgcn_mfma_f32_16x16x32_bf16(ka[nt][1], qb1, s, 0, 0, 0);
      sa[nt] = s;
    }
    // mask (tok==0 -> -inf); q-scale already folded into Q
#pragma unroll
    for (int nt = 0; nt < 4; nt++) {
      sa[nt][0] = mi[nt].x ? sa[nt][0] : -INFINITY;
      sa[nt][1] = mi[nt].y ? sa[nt][1] : -INFINITY;
      sa[nt][2] = mi[nt].z ? sa[nt][2] : -INFINITY;
      sa[nt][3] = mi[nt].w ? sa[nt][3] : -INFINITY;
    }

    // ---- tile max: in-lane tree (16) + 2 shfl over lh bits
    float t0 = fmaxf(fmaxf(sa[0][0], sa[0][1]), fmaxf(sa[0][2], sa[0][3]));
    float t1 = fmaxf(fmaxf(sa[1][0], sa[1][1]), fmaxf(sa[1][2], sa[1][3]));
    float t2 = fmaxf(fmaxf(sa[2][0], sa[2][1]), fmaxf(sa[2][2], sa[2][3]));
    float t3 = fmaxf(fmaxf(sa[3][0], sa[3][1]), fmaxf(sa[3][2], sa[3][3]));
    float tm = fmaxf(fmaxf(t0, t1), fmaxf(t2, t3));
    tm = fmaxf(tm, __shfl_xor(tm, 16));
    tm = fmaxf(tm, __shfl_xor(tm, 32));

    // ---- defer-max rescale (T13, THR=8)
    if (!__all(tm <= mrow + 8.0f)) {
      float nm = fmaxf(mrow, tm);
      float alpha = __expf(mrow - nm);
      mrow = nm;
      lrow *= alpha;
      float a0 = __shfl(alpha, lh * 4 + 0);
      float a1 = __shfl(alpha, lh * 4 + 1);
      float a2 = __shfl(alpha, lh * 4 + 2);
      float a3 = __shfl(alpha, lh * 4 + 3);
#pragma unroll
      for (int ht = 0; ht < 4; ht++) {
        o[ht][0] *= a0; o[ht][1] *= a1; o[ht][2] *= a2; o[ht][3] *= a3;
      }
    }

    // ---- p = exp(s - m), row sum
    float ts = 0.f;
#pragma unroll
    for (int nt = 0; nt < 4; nt++) {
#pragma unroll
      for (int r = 0; r < 4; r++) {
        float p = __expf(sa[nt][r] - mrow);
        sa[nt][r] = p;
        ts += p;
      }
    }
    ts += __shfl_xor(ts, 16);
    ts += __shfl_xor(ts, 32);
    lrow += ts;

    // ---- write P row (bf16), per-wave LDS, no barrier
#pragma unroll
    for (int nt = 0; nt < 4; nt++) {
      u32 plo = pack2bf(sa[nt][0], sa[nt][1]);
      u32 phi = pack2bf(sa[nt][2], sa[nt][3]);
      *(uint2*)&pw[pwr + nt * 16 + lh * 4] = make_uint2(plo, phi);
    }

    // ---- PV: O += P V
    bf16x8 ap0 = *(const bf16x8*)&pw[pwr + lh * 8];
    bf16x8 ap1 = *(const bf16x8*)&pw[pwr + 32 + lh * 8];
#pragma unroll
    for (int ht = 0; ht < 4; ht++) {
      o[ht] = __builtin_amdgcn_mfma_f32_16x16x32_bf16(ap0, vb[ht][0], o[ht], 0, 0, 0);
      o[ht] = __builtin_amdgcn_mfma_f32_16x16x32_bf16(ap1, vb[ht][1], o[ht], 0, 0, 0);
    }
  }

  // ---- write partials (unnormalized O, running m, l)
#pragma unroll
  for (int r = 0; r < 4; r++) {
    int rr = q0 + w * 16 + lh * 4 + r;
    float* pob = po + ((size_t)z * NB * SEQ + (size_t)b * SEQ + rr) * 64;
#pragma unroll
    for (int ht = 0; ht < 4; ht++) pob[ht * 16 + l15] = o[ht][r];
  }
  if (lh == 0) {
    int rr = q0 + w * 16 + l15;
    pmp[(size_t)z * NB * SEQ + (size_t)b * SEQ + rr] = mrow;
    plp[(size_t)z * NB * SEQ + (size_t)b * SEQ + rr] = lrow;
  }
}

// ---------------- merge SPLIT partials -> fp32 out
__global__ __launch_bounds__(256) void merge_k(
    const float* __restrict__ po, const float* __restrict__ pmp,
    const float* __restrict__ plp, float* __restrict__ out) {
  int tid = threadIdx.x;
  int row = blockIdx.x * 32 + (tid >> 3);
  int c8 = (tid & 7) * 8;
  const int RT = NB * SEQ;

  float m[SPLIT], lv[SPLIT];
  float M = -INFINITY;
#pragma unroll
  for (int s = 0; s < SPLIT; s++) {
    m[s] = pmp[(size_t)s * RT + row];
    lv[s] = plp[(size_t)s * RT + row];
    M = fmaxf(M, m[s]);
  }
  float o8[8];
#pragma unroll
  for (int j = 0; j < 8; j++) o8[j] = 0.f;
  float L = 0.f;
  if (M != -INFINITY) {
#pragma unroll
    for (int s = 0; s < SPLIT; s++) {
      float ws = __expf(m[s] - M);
      L += ws * lv[s];
      const float* p = po + ((size_t)s * RT + row) * 64 + c8;
#pragma unroll
      for (int j = 0; j < 8; j++) o8[j] += ws * p[j];
    }
  }
  float inv = (L > 0.f) ? 1.0f / L : 0.f;
  float* op = out + (size_t)row * 64 + c8;
#pragma unroll
  for (int j = 0; j < 8; j++) op[j] = o8[j] * inv;
}

extern "C" void kernel_launch(void* const* d_in, const int* in_sizes, int n_in,
                              void* d_out, int out_size, void* d_ws, size_t ws_size,
                              hipStream_t stream) {
  const float* X   = (const float*)d_in[0];
  const int*   mrk = (const int*)d_in[1];
  const float* Wq  = (const float*)d_in[2];
  const float* Wk  = (const float*)d_in[3];
  const float* Wv  = (const float*)d_in[4];
  const float* Aq  = (const float*)d_in[5];
  const float* Bq  = (const float*)d_in[6];
  const float* Ak  = (const float*)d_in[7];
  const float* Bk  = (const float*)d_in[8];
  const float* Av  = (const float*)d_in[9];
  const float* Bv  = (const float*)d_in[10];

  u16* weff = (u16*)d_ws;
  u16* qws  = (u16*)((char*)d_ws + (512 << 10));
  u16* kws  = qws + (size_t)16384 * 64;
  u16* vws  = kws + (size_t)16384 * 64;
  float* po  = (float*)((char*)d_ws + ((size_t)6656 << 10));
  float* pmp = po + (size_t)SPLIT * 16384 * 64;
  float* plp = pmp + (size_t)SPLIT * 16384;

  fold_k<<<192, 256, 0, stream>>>(Wq, Wk, Wv, Aq, Bq, Ak, Bk, Av, Bv, weff);
  proj_k<<<512, 512, 0, stream>>>(X, weff, qws, kws, vws);
  attn_k<<<dim3(32, 8, SPLIT), 256, 0, stream>>>(qws, kws, vws, mrk, po, pmp, plp);
  merge_k<<<512, 256, 0, stream>>>(po, pmp, plp, (float*)d_out);
}

// Round 7
// 95.392 us; speedup vs baseline: 1.3868x; 1.3868x over previous
//
#include <hip/hip_runtime.h>
#include <hip/hip_bf16.h>
#include <stdint.h>

#define EMB 1024
#define NB 8
#define SEQ 2048
#define RANK 8
#define SPLIT 4    // KV splits in flash attention

typedef __attribute__((ext_vector_type(8))) short bf16x8;
typedef __attribute__((ext_vector_type(4))) float f32x4;
typedef unsigned short u16;
typedef unsigned int u32;

__device__ __forceinline__ u16 f2bf(float f) {
  u32 u = __builtin_bit_cast(u32, f);
  u = (u + 0x7fffu + ((u >> 16) & 1u)) >> 16;   // RNE
  return (u16)u;
}
__device__ __forceinline__ u32 pack2bf(float lo, float hi) {
  return (u32)f2bf(lo) | ((u32)f2bf(hi) << 16);
}
__device__ __forceinline__ void gll16(const void* g, void* l) {
  __builtin_amdgcn_global_load_lds(
      (const __attribute__((address_space(1))) unsigned int*)g,
      (__attribute__((address_space(3))) unsigned int*)l, 16, 0, 0);
}

// ---------------- fold: Weff[m][e] = W[h][e] + 2*sum_r B[h][r]*A[r][e]
__global__ __launch_bounds__(256) void fold_k(
    const float* __restrict__ Wq, const float* __restrict__ Wk, const float* __restrict__ Wv,
    const float* __restrict__ Aq, const float* __restrict__ Bq,
    const float* __restrict__ Ak, const float* __restrict__ Bk,
    const float* __restrict__ Av, const float* __restrict__ Bv,
    u16* __restrict__ weff) {
  int m = blockIdx.x;
  int mat = m >> 6, h = m & 63;
  const float* W = mat == 0 ? Wq : (mat == 1 ? Wk : Wv);
  const float* A = mat == 0 ? Aq : (mat == 1 ? Ak : Av);
  const float* B = mat == 0 ? Bq : (mat == 1 ? Bk : Bv);
  float bb[RANK];
#pragma unroll
  for (int r = 0; r < RANK; r++) bb[r] = 2.0f * B[h * RANK + r];
  int e = threadIdx.x * 4;
  float4 w4 = *(const float4*)(W + h * EMB + e);
  float a0 = w4.x, a1 = w4.y, a2 = w4.z, a3 = w4.w;
#pragma unroll
  for (int r = 0; r < RANK; r++) {
    float4 av = *(const float4*)(A + r * EMB + e);
    a0 += bb[r] * av.x; a1 += bb[r] * av.y; a2 += bb[r] * av.z; a3 += bb[r] * av.w;
  }
  u16* o = weff + (size_t)m * EMB + e;
  o[0] = f2bf(a0); o[1] = f2bf(a1); o[2] = f2bf(a2); o[3] = f2bf(a3);
}

// ---------------- projection GEMM: C[16384,192] = X * Weff^T
// 1024 blocks x 256 thr (4 blocks/CU). 16 rows/block; waves col-split 4-way.
// X fp32 double-buffered via global_load_lds (column-chunk layout: chunk c16 =
// 4 floats x 16 rows = 256B; dest linear, conflict-free reads). W prefetched
// one full 128-k stage ahead. One barrier per stage.
__global__ __launch_bounds__(256) void proj_k(
    const float* __restrict__ X, const u16* __restrict__ weff,
    u16* __restrict__ qws, u16* __restrict__ kws, u16* __restrict__ vws) {
  __shared__ __align__(16) float xs[2][2048];   // 2 x 8KB

  int t = threadIdx.x;
  int w = t >> 6, l = t & 63;
  int l15 = l & 15, lh = l >> 4;
  int rbase = blockIdx.x * 16;

  // stage map: dest byte d = t*16 (+4096) -> chunk c16 = t>>4 (+16), row = l15
  const float* gsrc = X + (size_t)(rbase + l15) * EMB + ((t >> 4) << 2);
  char* lbs = (char*)&xs[0][0] + w * 1024;      // wave-uniform dest base

  const u16* wp[3];
#pragma unroll
  for (int tt = 0; tt < 3; tt++)
    wp[tt] = weff + (size_t)(w * 48 + tt * 16 + l15) * EMB + lh * 8;

  f32x4 acc[3];
  f32x4 zero = {0.f, 0.f, 0.f, 0.f};
#pragma unroll
  for (int tt = 0; tt < 3; tt++) acc[tt] = zero;

  bf16x8 wc[4][3], wn[4][3];

  // prologue: stage k0=0 into buf0; W(0) into wc
  gll16(gsrc, lbs);
  gll16(gsrc + 64, lbs + 4096);
#pragma unroll
  for (int j = 0; j < 4; j++)
#pragma unroll
    for (int tt = 0; tt < 3; tt++)
      wc[j][tt] = *(const bf16x8*)(wp[tt] + j * 32);
  __syncthreads();

  int cur = 0;
  for (int k0 = 0; k0 < EMB; k0 += 128) {
    int kn = k0 + 128;
    if (kn < EMB) {
      char* nb = (char*)&xs[0][0] + (cur ^ 1) * 8192 + w * 1024;
      gll16(gsrc + kn, nb);
      gll16(gsrc + kn + 64, nb + 4096);
#pragma unroll
      for (int j = 0; j < 4; j++)
#pragma unroll
        for (int tt = 0; tt < 3; tt++)
          wn[j][tt] = *(const bf16x8*)(wp[tt] + kn + j * 32);
    }
    const char* xb = (const char*)&xs[0][0] + cur * 8192 + l15 * 16;
#pragma unroll
    for (int j = 0; j < 4; j++) {
      int c0 = (j * 8 + lh * 2) * 256;
      f32x4 lo = *(const f32x4*)(xb + c0);
      f32x4 hi = *(const f32x4*)(xb + c0 + 256);
      union { bf16x8 v; u32 u[4]; } au;
      au.u[0] = pack2bf(lo.x, lo.y); au.u[1] = pack2bf(lo.z, lo.w);
      au.u[2] = pack2bf(hi.x, hi.y); au.u[3] = pack2bf(hi.z, hi.w);
#pragma unroll
      for (int tt = 0; tt < 3; tt++)
        acc[tt] = __builtin_amdgcn_mfma_f32_16x16x32_bf16(au.v, wc[j][tt], acc[tt], 0, 0, 0);
    }
    if (kn < EMB) {
#pragma unroll
      for (int j = 0; j < 4; j++)
#pragma unroll
        for (int tt = 0; tt < 3; tt++) wc[j][tt] = wn[j][tt];
    }
    __syncthreads();
    cur ^= 1;
  }

  // ---- epilogue: scatter to q (x0.125 folded) / k / v^T (bf16)
#pragma unroll
  for (int tt = 0; tt < 3; tt++) {
    int c = w * 48 + tt * 16 + l15;
#pragma unroll
    for (int r = 0; r < 4; r++) {
      int rr = rbase + lh * 4 + r;
      float av = acc[tt][r];
      if (c < 64) av *= 0.125f;
      u16 v = f2bf(av);
      if (c < 64) {
        qws[(size_t)rr * 64 + c] = v;
      } else if (c < 128) {
        kws[(size_t)rr * 64 + (c - 64)] = v;
      } else {
        int bb = rr >> 11, tok = rr & 2047;
        vws[((size_t)(bb * 64 + (c - 128))) * SEQ + tok] = v;
      }
    }
  }
}

// ---------------- flash attention, KV-split: grid (32 qtiles, 8 batch, SPLIT).
// Swapped QK^T (mfma(K,Q)); softmax lane-local + 2 shfl; defer-max (THR=8).
// K/V^T double-buffered in LDS via global_load_lds with source-permuted XOR
// swizzle (conflict-free b128 reads); stage(next) issued before compute(cur);
// one barrier per chunk.
__global__ __launch_bounds__(256) void attn_k(
    const u16* __restrict__ qws, const u16* __restrict__ kws, const u16* __restrict__ vws,
    const int* __restrict__ mrk,
    float* __restrict__ po, float* __restrict__ pmp, float* __restrict__ plp) {
  __shared__ __align__(16) u16 ks[2 * 4096];   // 2 x 8KB  [64 tok][64 h] swz
  __shared__ __align__(16) u16 vt[2 * 4096];   // 2 x 8KB  [64 h][64 tok] swz
  __shared__ __align__(16) u16 ps[4 * 1024];   // per-wave P [16 q][64 k] swz

  int b = blockIdx.y;
  int z = blockIdx.z;
  int q0 = blockIdx.x * 64;
  int t = threadIdx.x;
  int w = t >> 6, l = t & 63;
  int l15 = l & 15, lh = l >> 4;

  // staging map: per thread dest byte d = t*16 (+4096) -> row = t>>3 (+32),
  // within-row 16B slot = (t&7), source-swizzled by ((row&7)<<4)
  int srow = t >> 3;
  int ssw = (((t & 7) << 4) ^ ((srow & 7) << 4)) >> 1;   // elems
  char* ksb = (char*)ks + w * 1024;
  char* vtb = (char*)vt + w * 1024;

  const u16* qp = qws + ((size_t)(b * SEQ + q0 + w * 16 + l15)) * 64 + lh * 8;
  bf16x8 qb0 = *(const bf16x8*)qp;
  bf16x8 qb1 = *(const bf16x8*)(qp + 32);

  f32x4 o[4];
  f32x4 zero = {0.f, 0.f, 0.f, 0.f};
#pragma unroll
  for (int ht = 0; ht < 4; ht++) o[ht] = zero;
  float mrow = -30000.0f, lrow = 0.f;

  // read-side swizzled k-offsets (elems)
  int swz = (l15 & 7) << 4;
  int koffA = ((lh << 4) ^ swz) >> 1;
  int koffB = ((64 | (lh << 4)) ^ swz) >> 1;
  u16* psw = ps + w * 1024 + l15 * 64;

  const int NC = SEQ / 64 / SPLIT;
  int kk0 = z * (SEQ / SPLIT);

#define STAGE_KV(buf, kk)                                                          \
  do {                                                                             \
    gll16(kws + ((size_t)(b * SEQ + (kk) + srow)) * 64 + ssw,                      \
          ksb + (buf) * 8192);                                                     \
    gll16(kws + ((size_t)(b * SEQ + (kk) + srow + 32)) * 64 + ssw,                 \
          ksb + (buf) * 8192 + 4096);                                              \
    gll16(vws + ((size_t)(b * 64 + srow)) * SEQ + (kk) + ssw,                      \
          vtb + (buf) * 8192);                                                     \
    gll16(vws + ((size_t)(b * 64 + srow + 32)) * SEQ + (kk) + ssw,                 \
          vtb + (buf) * 8192 + 4096);                                              \
  } while (0)

  STAGE_KV(0, kk0);
  __syncthreads();

  int cur = 0;
  for (int kc = 0; kc < NC; kc++) {
    int kk = kk0 + kc * 64;
    if (kc + 1 < NC) STAGE_KV(cur ^ 1, kk + 64);

    // mask (per-lane, L2-hot)
    int4 mi[4];
#pragma unroll
    for (int nt = 0; nt < 4; nt++)
      mi[nt] = *(const int4*)(mrk + b * SEQ + kk + nt * 16 + lh * 4);

    // ---- K frags + S^T = K Q^T
    const u16* kb = ks + cur * 4096;
    f32x4 sa[4];
#pragma unroll
    for (int nt = 0; nt < 4; nt++) {
      const u16* kr = kb + (nt * 16 + l15) * 64;
      bf16x8 k0 = *(const bf16x8*)(kr + koffA);
      bf16x8 k1 = *(const bf16x8*)(kr + koffB);
      f32x4 s = zero;
      s = __builtin_amdgcn_mfma_f32_16x16x32_bf16(k0, qb0, s, 0, 0, 0);
      s = __builtin_amdgcn_mfma_f32_16x16x32_bf16(k1, qb1, s, 0, 0, 0);
      sa[nt] = s;
    }

    // ---- V frags issued early (latency hides under softmax)
    const u16* vbb = vt + cur * 4096;
    bf16x8 vb[4][2];
#pragma unroll
    for (int ht = 0; ht < 4; ht++) {
      const u16* vr = vbb + (ht * 16 + l15) * 64;
      vb[ht][0] = *(const bf16x8*)(vr + koffA);
      vb[ht][1] = *(const bf16x8*)(vr + koffB);
    }

    // ---- mask + softmax (lane-local tree + 2 shfl)
#pragma unroll
    for (int nt = 0; nt < 4; nt++) {
      sa[nt][0] = mi[nt].x ? sa[nt][0] : -INFINITY;
      sa[nt][1] = mi[nt].y ? sa[nt][1] : -INFINITY;
      sa[nt][2] = mi[nt].z ? sa[nt][2] : -INFINITY;
      sa[nt][3] = mi[nt].w ? sa[nt][3] : -INFINITY;
    }
    float t0 = fmaxf(fmaxf(sa[0][0], sa[0][1]), fmaxf(sa[0][2], sa[0][3]));
    float t1 = fmaxf(fmaxf(sa[1][0], sa[1][1]), fmaxf(sa[1][2], sa[1][3]));
    float t2 = fmaxf(fmaxf(sa[2][0], sa[2][1]), fmaxf(sa[2][2], sa[2][3]));
    float t3 = fmaxf(fmaxf(sa[3][0], sa[3][1]), fmaxf(sa[3][2], sa[3][3]));
    float tm = fmaxf(fmaxf(t0, t1), fmaxf(t2, t3));
    tm = fmaxf(tm, __shfl_xor(tm, 16));
    tm = fmaxf(tm, __shfl_xor(tm, 32));

    if (!__all(tm <= mrow + 8.0f)) {       // defer-max (T13)
      float nm = fmaxf(mrow, tm);
      float alpha = __expf(mrow - nm);
      mrow = nm;
      lrow *= alpha;
      float a0 = __shfl(alpha, lh * 4 + 0);
      float a1 = __shfl(alpha, lh * 4 + 1);
      float a2 = __shfl(alpha, lh * 4 + 2);
      float a3 = __shfl(alpha, lh * 4 + 3);
#pragma unroll
      for (int ht = 0; ht < 4; ht++) {
        o[ht][0] *= a0; o[ht][1] *= a1; o[ht][2] *= a2; o[ht][3] *= a3;
      }
    }

    float ts = 0.f;
#pragma unroll
    for (int nt = 0; nt < 4; nt++) {
#pragma unroll
      for (int r = 0; r < 4; r++) {
        float p = __expf(sa[nt][r] - mrow);
        sa[nt][r] = p;
        ts += p;
      }
    }
    ts += __shfl_xor(ts, 16);
    ts += __shfl_xor(ts, 32);
    lrow += ts;

    // ---- P -> per-wave LDS (swizzled), then A-frag read
#pragma unroll
    for (int nt = 0; nt < 4; nt++) {
      u32 plo = pack2bf(sa[nt][0], sa[nt][1]);
      u32 phi = pack2bf(sa[nt][2], sa[nt][3]);
      *(uint2*)&psw[(((nt * 32 + lh * 8) ^ swz) >> 1)] = make_uint2(plo, phi);
    }
    bf16x8 ap0 = *(const bf16x8*)(psw + koffA);
    bf16x8 ap1 = *(const bf16x8*)(psw + koffB);

    // ---- PV
#pragma unroll
    for (int ht = 0; ht < 4; ht++) {
      o[ht] = __builtin_amdgcn_mfma_f32_16x16x32_bf16(ap0, vb[ht][0], o[ht], 0, 0, 0);
      o[ht] = __builtin_amdgcn_mfma_f32_16x16x32_bf16(ap1, vb[ht][1], o[ht], 0, 0, 0);
    }
    __syncthreads();
    cur ^= 1;
  }
#undef STAGE_KV

  // ---- write partials (unnormalized O, running m, l)
#pragma unroll
  for (int r = 0; r < 4; r++) {
    int rr = q0 + w * 16 + lh * 4 + r;
    float* pob = po + ((size_t)z * NB * SEQ + (size_t)b * SEQ + rr) * 64;
#pragma unroll
    for (int ht = 0; ht < 4; ht++) pob[ht * 16 + l15] = o[ht][r];
  }
  if (lh == 0) {
    int rr = q0 + w * 16 + l15;
    pmp[(size_t)z * NB * SEQ + (size_t)b * SEQ + rr] = mrow;
    plp[(size_t)z * NB * SEQ + (size_t)b * SEQ + rr] = lrow;
  }
}

// ---------------- merge SPLIT partials -> fp32 out
__global__ __launch_bounds__(256) void merge_k(
    const float* __restrict__ po, const float* __restrict__ pmp,
    const float* __restrict__ plp, float* __restrict__ out) {
  int tid = threadIdx.x;
  int row = blockIdx.x * 32 + (tid >> 3);
  int c8 = (tid & 7) * 8;
  const int RT = NB * SEQ;

  float m[SPLIT], lv[SPLIT];
  float M = -INFINITY;
#pragma unroll
  for (int s = 0; s < SPLIT; s++) {
    m[s] = pmp[(size_t)s * RT + row];
    lv[s] = plp[(size_t)s * RT + row];
    M = fmaxf(M, m[s]);
  }
  float o8[8];
#pragma unroll
  for (int j = 0; j < 8; j++) o8[j] = 0.f;
  float L = 0.f;
  if (M != -INFINITY) {
#pragma unroll
    for (int s = 0; s < SPLIT; s++) {
      float ws = __expf(m[s] - M);
      L += ws * lv[s];
      const float* p = po + ((size_t)s * RT + row) * 64 + c8;
#pragma unroll
      for (int j = 0; j < 8; j++) o8[j] += ws * p[j];
    }
  }
  float inv = (L > 0.f) ? 1.0f / L : 0.f;
  float* op = out + (size_t)row * 64 + c8;
#pragma unroll
  for (int j = 0; j < 8; j++) op[j] = o8[j] * inv;
}

extern "C" void kernel_launch(void* const* d_in, const int* in_sizes, int n_in,
                              void* d_out, int out_size, void* d_ws, size_t ws_size,
                              hipStream_t stream) {
  const float* X   = (const float*)d_in[0];
  const int*   mrk = (const int*)d_in[1];
  const float* Wq  = (const float*)d_in[2];
  const float* Wk  = (const float*)d_in[3];
  const float* Wv  = (const float*)d_in[4];
  const float* Aq  = (const float*)d_in[5];
  const float* Bq  = (const float*)d_in[6];
  const float* Ak  = (const float*)d_in[7];
  const float* Bk  = (const float*)d_in[8];
  const float* Av  = (const float*)d_in[9];
  const float* Bv  = (const float*)d_in[10];

  u16* weff = (u16*)d_ws;
  u16* qws  = (u16*)((char*)d_ws + (512 << 10));
  u16* kws  = qws + (size_t)16384 * 64;
  u16* vws  = kws + (size_t)16384 * 64;
  float* po  = (float*)((char*)d_ws + ((size_t)6656 << 10));
  float* pmp = po + (size_t)SPLIT * 16384 * 64;
  float* plp = pmp + (size_t)SPLIT * 16384;

  fold_k<<<192, 256, 0, stream>>>(Wq, Wk, Wv, Aq, Bq, Ak, Bk, Av, Bv, weff);
  proj_k<<<1024, 256, 0, stream>>>(X, weff, qws, kws, vws);
  attn_k<<<dim3(32, 8, SPLIT), 256, 0, stream>>>(qws, kws, vws, mrk, po, pmp, plp);
  merge_k<<<512, 256, 0, stream>>>(po, pmp, plp, (float*)d_out);
}

// Round 9
// 68.286 us; speedup vs baseline: 1.9373x; 1.3970x over previous
//
#include <hip/hip_runtime.h>
#include <hip/hip_bf16.h>
#include <stdint.h>

#define EMB 1024
#define NB 8
#define SEQ 2048
#define RANK 8
#define SPLIT 4    // KV splits in flash attention

// proj geometry
#define BM 64      // rows per block
#define BK 64      // k per stage
#define NSTG 16    // EMB/BK
#define BUFB 32768 // 8KB X(bf16) + 24KB W per stage buffer
#define NBUF 3

typedef __attribute__((ext_vector_type(8))) short bf16x8;
typedef __attribute__((ext_vector_type(4))) float f32x4;
typedef unsigned short u16;
typedef unsigned int u32;

__device__ __forceinline__ u16 f2bf(float f) {
  u32 u = __builtin_bit_cast(u32, f);
  u = (u + 0x7fffu + ((u >> 16) & 1u)) >> 16;   // RNE
  return (u16)u;
}
__device__ __forceinline__ u32 pk2(float lo, float hi) {
  return (u32)f2bf(lo) | ((u32)f2bf(hi) << 16);
}
__device__ __forceinline__ void gll16(const void* g, void* l) {
  __builtin_amdgcn_global_load_lds(
      (const __attribute__((address_space(1))) unsigned int*)g,
      (__attribute__((address_space(3))) unsigned int*)l, 16, 0, 0);
}

#define PBAR()   asm volatile("s_barrier" ::: "memory")
#define WAITV(n) asm volatile("s_waitcnt vmcnt(" #n ")" ::: "memory")
#define WAITL()  asm volatile("s_waitcnt lgkmcnt(0)" ::: "memory")

// ---------------- fold: Weff[m][e] = W[h][e] + 2*sum_r B[h][r]*A[r][e]
__global__ __launch_bounds__(256) void fold_k(
    const float* __restrict__ Wq, const float* __restrict__ Wk, const float* __restrict__ Wv,
    const float* __restrict__ Aq, const float* __restrict__ Bq,
    const float* __restrict__ Ak, const float* __restrict__ Bk,
    const float* __restrict__ Av, const float* __restrict__ Bv,
    u16* __restrict__ weff) {
  int m = blockIdx.x;
  int mat = m >> 6, h = m & 63;
  const float* W = mat == 0 ? Wq : (mat == 1 ? Wk : Wv);
  const float* A = mat == 0 ? Aq : (mat == 1 ? Ak : Av);
  const float* B = mat == 0 ? Bq : (mat == 1 ? Bk : Bv);
  float bb[RANK];
#pragma unroll
  for (int r = 0; r < RANK; r++) bb[r] = 2.0f * B[h * RANK + r];
  int e = threadIdx.x * 4;
  float4 w4 = *(const float4*)(W + h * EMB + e);
  float a0 = w4.x, a1 = w4.y, a2 = w4.z, a3 = w4.w;
#pragma unroll
  for (int r = 0; r < RANK; r++) {
    float4 av = *(const float4*)(A + r * EMB + e);
    a0 += bb[r] * av.x; a1 += bb[r] * av.y; a2 += bb[r] * av.z; a3 += bb[r] * av.w;
  }
  u16* o = weff + (size_t)m * EMB + e;
  o[0] = f2bf(a0); o[1] = f2bf(a1); o[2] = f2bf(a2); o[3] = f2bf(a3);
}

// ---------------- projection GEMM: C[16384,192] = X * Weff^T
// 256 blocks x 512 thr, 64 rows/block, 1 block/CU (96KB dynamic LDS).
// Producer/consumer: waves 6-7 stage X (fp32->bf16 reg-staged, ds_write) and
// W (gll16, source-XOR-swizzled) into a 3-deep pipeline with COUNTED vmcnt
// (never 0 in steady state) + raw s_barrier (1/stage). Waves 0-5 compute
// 64 rows x 32 cols each: 8 A-reads + 4 B-reads + 16 MFMA per stage, no vmem.
__global__ __launch_bounds__(512) void proj_k(
    const float* __restrict__ X, const u16* __restrict__ weff,
    u16* __restrict__ qws, u16* __restrict__ kws, u16* __restrict__ vws) {
  extern __shared__ __align__(16) char smem[];   // NBUF * BUFB = 96KB

  int t = threadIdx.x;
  int w = t >> 6, l = t & 63;
  int rbase = blockIdx.x * BM;

  if (w >= 6) {
    // ======== producer (waves 6,7 = 128 threads) ========
    int q = w - 6;                 // 0,1
    int p = q * 64 + l;            // 0..127
    int xrow = p & 63;
    int xh = p >> 6;               // 0/1 selects odd/even kc8 pairs
    const float* xsrc = X + (size_t)(rbase + xrow) * EMB + xh * 8;
    int wkoff = ((l & 7) ^ (l >> 3)) << 3;   // source-side XOR swizzle (elems)
    int wc0 = l >> 3;

    float4 xr0[8], xr1[8];

#define ISSUE_X(st, xr) do {                                              \
    const float* s_ = xsrc + (st) * BK;                                   \
    _Pragma("unroll")                                                     \
    for (int wi_ = 0; wi_ < 4; wi_++) {                                   \
      xr[wi_*2]   = *(const float4*)(s_ + wi_ * 16);                      \
      xr[wi_*2+1] = *(const float4*)(s_ + wi_ * 16 + 4);                  \
    } } while (0)

#define WRITE_X(bufp, xr) do {                                            \
    _Pragma("unroll")                                                     \
    for (int wi_ = 0; wi_ < 4; wi_++) {                                   \
      uint4 v_;                                                           \
      v_.x = pk2(xr[wi_*2].x,   xr[wi_*2].y);                             \
      v_.y = pk2(xr[wi_*2].z,   xr[wi_*2].w);                             \
      v_.z = pk2(xr[wi_*2+1].x, xr[wi_*2+1].y);                           \
      v_.w = pk2(xr[wi_*2+1].z, xr[wi_*2+1].w);                           \
      *(uint4*)((bufp) + (wi_*2 + xh) * 1024 + xrow * 16) = v_;           \
    } } while (0)

#define ISSUE_W(st, bufp) do {                                            \
    _Pragma("unroll")                                                     \
    for (int i_ = 0; i_ < 12; i_++) { int wj_ = q * 12 + i_;              \
      gll16(weff + (size_t)(wj_ * 8 + wc0) * EMB + (st) * BK + wkoff,     \
            (bufp) + 8192 + wj_ * 1024);                                  \
    } } while (0)

    // prologue: stage 0 fully, stage 1 loads in flight
    ISSUE_X(0, xr0); ISSUE_W(0, smem);
    ISSUE_X(1, xr1); ISSUE_W(1, smem + BUFB);
    WRITE_X(smem, xr0);          // compiler waits X0 regs
    WAITV(20);                   // W0 landed (X1+W1 = 20 may stay in flight)
    WAITL();

    for (int s = 0; s < NSTG; s++) {
      PBAR();
      char* nbuf = smem + ((s + 2) % NBUF) * BUFB;
      char* wbuf = smem + ((s + 1) % NBUF) * BUFB;
      if ((s & 1) == 0) {
        if (s + 2 < NSTG) { ISSUE_X(s + 2, xr0); ISSUE_W(s + 2, nbuf); }
        if (s + 1 < NSTG) WRITE_X(wbuf, xr1);
      } else {
        if (s + 2 < NSTG) { ISSUE_X(s + 2, xr1); ISSUE_W(s + 2, nbuf); }
        if (s + 1 < NSTG) WRITE_X(wbuf, xr0);
      }
      if (s + 2 < NSTG) { WAITV(20); } else { WAITV(0); }   // W(s+1) landed
      WAITL();                                              // X(s+1) writes done
    }
#undef ISSUE_X
#undef WRITE_X
#undef ISSUE_W
  } else {
    // ======== consumer (waves 0-5): 64 rows x cols [w*32, w*32+32) ========
    int l15 = l & 15, lh = l >> 4;
    f32x4 acc[4][2];
    f32x4 zero = {0.f, 0.f, 0.f, 0.f};
#pragma unroll
    for (int rt = 0; rt < 4; rt++)
#pragma unroll
      for (int ct = 0; ct < 2; ct++) acc[rt][ct] = zero;
    int swz = (l15 & 7) << 4;

    for (int s = 0; s < NSTG; s++) {
      PBAR();
      const char* buf = smem + (s % NBUF) * BUFB;
#pragma unroll
      for (int j = 0; j < 2; j++) {
        bf16x8 a[4];
#pragma unroll
        for (int rt = 0; rt < 4; rt++)
          a[rt] = *(const bf16x8*)(buf + (j * 4 + lh) * 1024 + (rt * 16 + l15) * 16);
#pragma unroll
        for (int ct = 0; ct < 2; ct++) {
          int col = (w * 2 + ct) * 16 + l15;
          bf16x8 bf = *(const bf16x8*)(buf + 8192 + col * 128 +
                                       ((j * 64 + lh * 16) ^ swz));
#pragma unroll
          for (int rt = 0; rt < 4; rt++)
            acc[rt][ct] = __builtin_amdgcn_mfma_f32_16x16x32_bf16(a[rt], bf, acc[rt][ct], 0, 0, 0);
        }
      }
    }

    // epilogue: scatter to q (x0.125 folded) / k / v^T (bf16)
#pragma unroll
    for (int rt = 0; rt < 4; rt++)
#pragma unroll
      for (int ct = 0; ct < 2; ct++) {
        int c = (w * 2 + ct) * 16 + l15;
#pragma unroll
        for (int r = 0; r < 4; r++) {
          int rr = rbase + rt * 16 + lh * 4 + r;
          float av = acc[rt][ct][r];
          if (c < 64) av *= 0.125f;
          u16 v = f2bf(av);
          if (c < 64) {
            qws[(size_t)rr * 64 + c] = v;
          } else if (c < 128) {
            kws[(size_t)rr * 64 + (c - 64)] = v;
          } else {
            int bb = rr >> 11, tok = rr & 2047;
            vws[((size_t)(bb * 64 + (c - 128))) * SEQ + tok] = v;
          }
        }
      }
  }
}

// ---------------- flash attention, KV-split: grid (32 qtiles, 8 batch, SPLIT).
__global__ __launch_bounds__(256) void attn_k(
    const u16* __restrict__ qws, const u16* __restrict__ kws, const u16* __restrict__ vws,
    const int* __restrict__ mrk,
    float* __restrict__ po, float* __restrict__ pmp, float* __restrict__ plp) {
  __shared__ __align__(16) u16 ks[2 * 4096];
  __shared__ __align__(16) u16 vt[2 * 4096];
  __shared__ __align__(16) u16 ps[4 * 1024];

  int b = blockIdx.y;
  int z = blockIdx.z;
  int q0 = blockIdx.x * 64;
  int t = threadIdx.x;
  int w = t >> 6, l = t & 63;
  int l15 = l & 15, lh = l >> 4;

  int srow = t >> 3;
  int ssw = (((t & 7) << 4) ^ ((srow & 7) << 4)) >> 1;
  char* ksb = (char*)ks + w * 1024;
  char* vtb = (char*)vt + w * 1024;

  const u16* qp = qws + ((size_t)(b * SEQ + q0 + w * 16 + l15)) * 64 + lh * 8;
  bf16x8 qb0 = *(const bf16x8*)qp;
  bf16x8 qb1 = *(const bf16x8*)(qp + 32);

  f32x4 o[4];
  f32x4 zero = {0.f, 0.f, 0.f, 0.f};
#pragma unroll
  for (int ht = 0; ht < 4; ht++) o[ht] = zero;
  float mrow = -30000.0f, lrow = 0.f;

  int swz = (l15 & 7) << 4;
  int koffA = ((lh << 4) ^ swz) >> 1;
  int koffB = ((64 | (lh << 4)) ^ swz) >> 1;
  u16* psw = ps + w * 1024 + l15 * 64;

  const int NC = SEQ / 64 / SPLIT;
  int kk0 = z * (SEQ / SPLIT);

#define STAGE_KV(buf, kk)                                                          \
  do {                                                                             \
    gll16(kws + ((size_t)(b * SEQ + (kk) + srow)) * 64 + ssw,                      \
          ksb + (buf) * 8192);                                                     \
    gll16(kws + ((size_t)(b * SEQ + (kk) + srow + 32)) * 64 + ssw,                 \
          ksb + (buf) * 8192 + 4096);                                              \
    gll16(vws + ((size_t)(b * 64 + srow)) * SEQ + (kk) + ssw,                      \
          vtb + (buf) * 8192);                                                     \
    gll16(vws + ((size_t)(b * 64 + srow + 32)) * SEQ + (kk) + ssw,                 \
          vtb + (buf) * 8192 + 4096);                                              \
  } while (0)

  STAGE_KV(0, kk0);
  __syncthreads();

  int cur = 0;
  for (int kc = 0; kc < NC; kc++) {
    int kk = kk0 + kc * 64;
    if (kc + 1 < NC) STAGE_KV(cur ^ 1, kk + 64);

    int4 mi[4];
#pragma unroll
    for (int nt = 0; nt < 4; nt++)
      mi[nt] = *(const int4*)(mrk + b * SEQ + kk + nt * 16 + lh * 4);

    const u16* kb = ks + cur * 4096;
    f32x4 sa[4];
#pragma unroll
    for (int nt = 0; nt < 4; nt++) {
      const u16* kr = kb + (nt * 16 + l15) * 64;
      bf16x8 k0 = *(const bf16x8*)(kr + koffA);
      bf16x8 k1 = *(const bf16x8*)(kr + koffB);
      f32x4 s = zero;
      s = __builtin_amdgcn_mfma_f32_16x16x32_bf16(k0, qb0, s, 0, 0, 0);
      s = __builtin_amdgcn_mfma_f32_16x16x32_bf16(k1, qb1, s, 0, 0, 0);
      sa[nt] = s;
    }

    const u16* vbb = vt + cur * 4096;
    bf16x8 vb[4][2];
#pragma unroll
    for (int ht = 0; ht < 4; ht++) {
      const u16* vr = vbb + (ht * 16 + l15) * 64;
      vb[ht][0] = *(const bf16x8*)(vr + koffA);
      vb[ht][1] = *(const bf16x8*)(vr + koffB);
    }

#pragma unroll
    for (int nt = 0; nt < 4; nt++) {
      sa[nt][0] = mi[nt].x ? sa[nt][0] : -INFINITY;
      sa[nt][1] = mi[nt].y ? sa[nt][1] : -INFINITY;
      sa[nt][2] = mi[nt].z ? sa[nt][2] : -INFINITY;
      sa[nt][3] = mi[nt].w ? sa[nt][3] : -INFINITY;
    }
    float t0 = fmaxf(fmaxf(sa[0][0], sa[0][1]), fmaxf(sa[0][2], sa[0][3]));
    float t1 = fmaxf(fmaxf(sa[1][0], sa[1][1]), fmaxf(sa[1][2], sa[1][3]));
    float t2 = fmaxf(fmaxf(sa[2][0], sa[2][1]), fmaxf(sa[2][2], sa[2][3]));
    float t3 = fmaxf(fmaxf(sa[3][0], sa[3][1]), fmaxf(sa[3][2], sa[3][3]));
    float tm = fmaxf(fmaxf(t0, t1), fmaxf(t2, t3));
    tm = fmaxf(tm, __shfl_xor(tm, 16));
    tm = fmaxf(tm, __shfl_xor(tm, 32));

    if (!__all(tm <= mrow + 8.0f)) {       // defer-max (T13)
      float nm = fmaxf(mrow, tm);
      float alpha = __expf(mrow - nm);
      mrow = nm;
      lrow *= alpha;
      float a0 = __shfl(alpha, lh * 4 + 0);
      float a1 = __shfl(alpha, lh * 4 + 1);
      float a2 = __shfl(alpha, lh * 4 + 2);
      float a3 = __shfl(alpha, lh * 4 + 3);
#pragma unroll
      for (int ht = 0; ht < 4; ht++) {
        o[ht][0] *= a0; o[ht][1] *= a1; o[ht][2] *= a2; o[ht][3] *= a3;
      }
    }

    float ts = 0.f;
#pragma unroll
    for (int nt = 0; nt < 4; nt++) {
#pragma unroll
      for (int r = 0; r < 4; r++) {
        float p = __expf(sa[nt][r] - mrow);
        sa[nt][r] = p;
        ts += p;
      }
    }
    ts += __shfl_xor(ts, 16);
    ts += __shfl_xor(ts, 32);
    lrow += ts;

#pragma unroll
    for (int nt = 0; nt < 4; nt++) {
      u32 plo = pk2(sa[nt][0], sa[nt][1]);
      u32 phi = pk2(sa[nt][2], sa[nt][3]);
      *(uint2*)&psw[(((nt * 32 + lh * 8) ^ swz) >> 1)] = make_uint2(plo, phi);
    }
    bf16x8 ap0 = *(const bf16x8*)(psw + koffA);
    bf16x8 ap1 = *(const bf16x8*)(psw + koffB);

#pragma unroll
    for (int ht = 0; ht < 4; ht++) {
      o[ht] = __builtin_amdgcn_mfma_f32_16x16x32_bf16(ap0, vb[ht][0], o[ht], 0, 0, 0);
      o[ht] = __builtin_amdgcn_mfma_f32_16x16x32_bf16(ap1, vb[ht][1], o[ht], 0, 0, 0);
    }
    __syncthreads();
    cur ^= 1;
  }
#undef STAGE_KV

#pragma unroll
  for (int r = 0; r < 4; r++) {
    int rr = q0 + w * 16 + lh * 4 + r;
    float* pob = po + ((size_t)z * NB * SEQ + (size_t)b * SEQ + rr) * 64;
#pragma unroll
    for (int ht = 0; ht < 4; ht++) pob[ht * 16 + l15] = o[ht][r];
  }
  if (lh == 0) {
    int rr = q0 + w * 16 + l15;
    pmp[(size_t)z * NB * SEQ + (size_t)b * SEQ + rr] = mrow;
    plp[(size_t)z * NB * SEQ + (size_t)b * SEQ + rr] = lrow;
  }
}

// ---------------- merge SPLIT partials -> fp32 out
__global__ __launch_bounds__(256) void merge_k(
    const float* __restrict__ po, const float* __restrict__ pmp,
    const float* __restrict__ plp, float* __restrict__ out) {
  int tid = threadIdx.x;
  int row = blockIdx.x * 32 + (tid >> 3);
  int c8 = (tid & 7) * 8;
  const int RT = NB * SEQ;

  float m[SPLIT], lv[SPLIT];
  float M = -INFINITY;
#pragma unroll
  for (int s = 0; s < SPLIT; s++) {
    m[s] = pmp[(size_t)s * RT + row];
    lv[s] = plp[(size_t)s * RT + row];
    M = fmaxf(M, m[s]);
  }
  float o8[8];
#pragma unroll
  for (int j = 0; j < 8; j++) o8[j] = 0.f;
  float L = 0.f;
  if (M != -INFINITY) {
#pragma unroll
    for (int s = 0; s < SPLIT; s++) {
      float ws = __expf(m[s] - M);
      L += ws * lv[s];
      const float* p = po + ((size_t)s * RT + row) * 64 + c8;
#pragma unroll
      for (int j = 0; j < 8; j++) o8[j] += ws * p[j];
    }
  }
  float inv = (L > 0.f) ? 1.0f / L : 0.f;
  float* op = out + (size_t)row * 64 + c8;
#pragma unroll
  for (int j = 0; j < 8; j++) op[j] = o8[j] * inv;
}

extern "C" void kernel_launch(void* const* d_in, const int* in_sizes, int n_in,
                              void* d_out, int out_size, void* d_ws, size_t ws_size,
                              hipStream_t stream) {
  const float* X   = (const float*)d_in[0];
  const int*   mrk = (const int*)d_in[1];
  const float* Wq  = (const float*)d_in[2];
  const float* Wk  = (const float*)d_in[3];
  const float* Wv  = (const float*)d_in[4];
  const float* Aq  = (const float*)d_in[5];
  const float* Bq  = (const float*)d_in[6];
  const float* Ak  = (const float*)d_in[7];
  const float* Bk  = (const float*)d_in[8];
  const float* Av  = (const float*)d_in[9];
  const float* Bv  = (const float*)d_in[10];

  u16* weff = (u16*)d_ws;
  u16* qws  = (u16*)((char*)d_ws + (512 << 10));
  u16* kws  = qws + (size_t)16384 * 64;
  u16* vws  = kws + (size_t)16384 * 64;
  float* po  = (float*)((char*)d_ws + ((size_t)6656 << 10));
  float* pmp = po + (size_t)SPLIT * 16384 * 64;
  float* plp = pmp + (size_t)SPLIT * 16384;

  // allow 96KB dynamic LDS for proj_k (idempotent, host-side, capture-safe)
  (void)hipFuncSetAttribute((const void*)proj_k,
                            hipFuncAttributeMaxDynamicSharedMemorySize, NBUF * BUFB);

  fold_k<<<192, 256, 0, stream>>>(Wq, Wk, Wv, Aq, Bq, Ak, Bk, Av, Bv, weff);
  proj_k<<<256, 512, NBUF * BUFB, stream>>>(X, weff, qws, kws, vws);
  attn_k<<<dim3(32, 8, SPLIT), 256, 0, stream>>>(qws, kws, vws, mrk, po, pmp, plp);
  merge_k<<<512, 256, 0, stream>>>(po, pmp, plp, (float*)d_out);
}

// Round 10
// 61.669 us; speedup vs baseline: 2.1452x; 1.1073x over previous
//
#include <hip/hip_runtime.h>
#include <hip/hip_bf16.h>
#include <stdint.h>

#define EMB 1024
#define NB 8
#define SEQ 2048
#define RANK 8
#define SPLIT 4    // KV splits in flash attention

// proj geometry
#define BM 64      // rows per block
#define BK 64      // k per stage
#define NSTG 16    // EMB/BK
#define BUFB 40960 // 16KB X(fp32) + 24KB W(bf16) per stage buffer
#define NBUF 3     // 120KB dynamic LDS

typedef __attribute__((ext_vector_type(8))) short bf16x8;
typedef __attribute__((ext_vector_type(4))) float f32x4;
typedef unsigned short u16;
typedef unsigned int u32;

__device__ __forceinline__ u16 f2bf(float f) {
  u32 u = __builtin_bit_cast(u32, f);
  u = (u + 0x7fffu + ((u >> 16) & 1u)) >> 16;   // RNE
  return (u16)u;
}
__device__ __forceinline__ u32 pk2(float lo, float hi) {
  return (u32)f2bf(lo) | ((u32)f2bf(hi) << 16);
}
__device__ __forceinline__ u32 cvtpk(float lo, float hi) {
  __hip_bfloat162 h = __float22bfloat162_rn(make_float2(lo, hi));  // HW pk cvt, RNE
  u32 u; __builtin_memcpy(&u, &h, 4); return u;
}
__device__ __forceinline__ void gll16(const void* g, void* l) {
  __builtin_amdgcn_global_load_lds(
      (const __attribute__((address_space(1))) unsigned int*)g,
      (__attribute__((address_space(3))) unsigned int*)l, 16, 0, 0);
}

#define PBAR()   asm volatile("s_barrier" ::: "memory")
#define WAITV(n) asm volatile("s_waitcnt vmcnt(" #n ")" ::: "memory")

// ---------------- fold: Weff[m][e] = W[h][e] + 2*sum_r B[h][r]*A[r][e]
__global__ __launch_bounds__(256) void fold_k(
    const float* __restrict__ Wq, const float* __restrict__ Wk, const float* __restrict__ Wv,
    const float* __restrict__ Aq, const float* __restrict__ Bq,
    const float* __restrict__ Ak, const float* __restrict__ Bk,
    const float* __restrict__ Av, const float* __restrict__ Bv,
    u16* __restrict__ weff) {
  int m = blockIdx.x;
  int mat = m >> 6, h = m & 63;
  const float* W = mat == 0 ? Wq : (mat == 1 ? Wk : Wv);
  const float* A = mat == 0 ? Aq : (mat == 1 ? Ak : Av);
  const float* B = mat == 0 ? Bq : (mat == 1 ? Bk : Bv);
  float bb[RANK];
#pragma unroll
  for (int r = 0; r < RANK; r++) bb[r] = 2.0f * B[h * RANK + r];
  int e = threadIdx.x * 4;
  float4 w4 = *(const float4*)(W + h * EMB + e);
  float a0 = w4.x, a1 = w4.y, a2 = w4.z, a3 = w4.w;
#pragma unroll
  for (int r = 0; r < RANK; r++) {
    float4 av = *(const float4*)(A + r * EMB + e);
    a0 += bb[r] * av.x; a1 += bb[r] * av.y; a2 += bb[r] * av.z; a3 += bb[r] * av.w;
  }
  u16* o = weff + (size_t)m * EMB + e;
  o[0] = f2bf(a0); o[1] = f2bf(a1); o[2] = f2bf(a2); o[3] = f2bf(a3);
}

// ---------------- projection GEMM: C[16384,192] = X * Weff^T
// 256 blocks x 512 thr, 64 rows/block, 1 block/CU (120KB dynamic LDS).
// Producer waves 6-7: pure gll16 issuer (8 X fp32 + 12 W bf16 per wave per
// stage), issued 2 barriers ahead; counted WAITV(20) (never 0 steady-state);
// one s_barrier per stage. XOR swizzle carried on SOURCE addresses; LDS dest
// linear. Consumer waves 0-5: 64 rows x 32 cols each; fp32 A-frags read
// swizzled + pk-cvt to bf16; B bf16 read swizzled; 16 MFMA/stage; no vmem.
__global__ __launch_bounds__(512) void proj_k(
    const float* __restrict__ X, const u16* __restrict__ weff,
    u16* __restrict__ qws, u16* __restrict__ kws, u16* __restrict__ vws) {
  extern __shared__ __align__(16) char smem[];   // NBUF * BUFB

  int t = threadIdx.x;
  int w = t >> 6, l = t & 63;
  int rbase = blockIdx.x * BM;

  if (w >= 6) {
    // ======== producer (waves 6,7) ========
    int q = w - 6;                           // 0,1
    int wkoff = ((l & 7) ^ (l >> 3)) * 8;    // W source swizzle (elems)
    int wc0 = l >> 3;
    int lr4 = l >> 4;                        // 0..3 row-in-instr
    int l15 = l & 15;

#define ISSUE(st, bufp) do {                                                   \
    _Pragma("unroll")                                                          \
    for (int i_ = 0; i_ < 8; i_++) {                                           \
      int rrel_ = q * 32 + i_ * 4 + lr4;                                       \
      int xo_ = 4 * (l15 ^ (rrel_ & 7));     /* X source swizzle (floats) */   \
      gll16(X + (size_t)(rbase + rrel_) * EMB + (st) * BK + xo_,               \
            (bufp) + q * 8192 + i_ * 1024);                                    \
    }                                                                          \
    _Pragma("unroll")                                                          \
    for (int i_ = 0; i_ < 12; i_++) { int wj_ = q * 12 + i_;                   \
      gll16(weff + (size_t)(wj_ * 8 + wc0) * EMB + (st) * BK + wkoff,          \
            (bufp) + 16384 + wj_ * 1024);                                      \
    } } while (0)

    // prologue: batches 0 and 1 in flight; batch 0 landed
    ISSUE(0, smem);
    ISSUE(1, smem + BUFB);
    WAITV(20);
    for (int s = 0; s < NSTG; s++) {
      PBAR();                                          // consumers start stage s
      if (s + 2 < NSTG) {
        ISSUE(s + 2, smem + ((s + 2) % NBUF) * BUFB);  // buf[s] being read: disjoint
        WAITV(20);                                     // batch s+1 landed
      } else if (s + 1 < NSTG) {
        WAITV(0);                                      // drain tail
      }
    }
#undef ISSUE
  } else {
    // ======== consumer (waves 0-5): 64 rows x cols [w*32, w*32+32) ========
    int l15 = l & 15, lh = l >> 4;
    f32x4 acc[4][2];
    f32x4 zero = {0.f, 0.f, 0.f, 0.f};
#pragma unroll
    for (int rt = 0; rt < 4; rt++)
#pragma unroll
      for (int ct = 0; ct < 2; ct++) acc[rt][ct] = zero;

    for (int s = 0; s < NSTG; s++) {
      PBAR();
      const char* bx = smem + (s % NBUF) * BUFB;   // X fp32 [64][256B] swz
      const char* bw = bx + 16384;                 // W bf16 [192][128B] swz
#pragma unroll
      for (int j = 0; j < 2; j++) {
        bf16x8 a[4];
#pragma unroll
        for (int rt = 0; rt < 4; rt++) {
          int r = rt * 16 + l15;
          int sw = (r & 7) << 4;
          const char* base = bx + r * 256;
          f32x4 lo = *(const f32x4*)(base + ((j * 128 + lh * 32) ^ sw));
          f32x4 hi = *(const f32x4*)(base + ((j * 128 + lh * 32 + 16) ^ sw));
          union { bf16x8 v; u32 u[4]; } au;
          au.u[0] = cvtpk(lo.x, lo.y); au.u[1] = cvtpk(lo.z, lo.w);
          au.u[2] = cvtpk(hi.x, hi.y); au.u[3] = cvtpk(hi.z, hi.w);
          a[rt] = au.v;
        }
#pragma unroll
        for (int ct = 0; ct < 2; ct++) {
          int col = (w * 2 + ct) * 16 + l15;
          bf16x8 bf = *(const bf16x8*)(bw + col * 128 +
                                       ((j * 64 + lh * 16) ^ ((col & 7) << 4)));
#pragma unroll
          for (int rt = 0; rt < 4; rt++)
            acc[rt][ct] = __builtin_amdgcn_mfma_f32_16x16x32_bf16(a[rt], bf, acc[rt][ct], 0, 0, 0);
        }
      }
    }

    // epilogue: scatter to q (x0.125 folded) / k / v^T (bf16)
#pragma unroll
    for (int rt = 0; rt < 4; rt++)
#pragma unroll
      for (int ct = 0; ct < 2; ct++) {
        int c = (w * 2 + ct) * 16 + l15;
#pragma unroll
        for (int r = 0; r < 4; r++) {
          int rr = rbase + rt * 16 + lh * 4 + r;
          float av = acc[rt][ct][r];
          if (c < 64) av *= 0.125f;
          u16 v = f2bf(av);
          if (c < 64) {
            qws[(size_t)rr * 64 + c] = v;
          } else if (c < 128) {
            kws[(size_t)rr * 64 + (c - 64)] = v;
          } else {
            int bb = rr >> 11, tok = rr & 2047;
            vws[((size_t)(bb * 64 + (c - 128))) * SEQ + tok] = v;
          }
        }
      }
  }
}

// ---------------- flash attention, KV-split: grid (32 qtiles, 8 batch, SPLIT).
__global__ __launch_bounds__(256) void attn_k(
    const u16* __restrict__ qws, const u16* __restrict__ kws, const u16* __restrict__ vws,
    const int* __restrict__ mrk,
    float* __restrict__ po, float* __restrict__ pmp, float* __restrict__ plp) {
  __shared__ __align__(16) u16 ks[2 * 4096];
  __shared__ __align__(16) u16 vt[2 * 4096];
  __shared__ __align__(16) u16 ps[4 * 1024];

  int b = blockIdx.y;
  int z = blockIdx.z;
  int q0 = blockIdx.x * 64;
  int t = threadIdx.x;
  int w = t >> 6, l = t & 63;
  int l15 = l & 15, lh = l >> 4;

  int srow = t >> 3;
  int ssw = (((t & 7) << 4) ^ ((srow & 7) << 4)) >> 1;
  char* ksb = (char*)ks + w * 1024;
  char* vtb = (char*)vt + w * 1024;

  const u16* qp = qws + ((size_t)(b * SEQ + q0 + w * 16 + l15)) * 64 + lh * 8;
  bf16x8 qb0 = *(const bf16x8*)qp;
  bf16x8 qb1 = *(const bf16x8*)(qp + 32);

  f32x4 o[4];
  f32x4 zero = {0.f, 0.f, 0.f, 0.f};
#pragma unroll
  for (int ht = 0; ht < 4; ht++) o[ht] = zero;
  float mrow = -30000.0f, lrow = 0.f;

  int swz = (l15 & 7) << 4;
  int koffA = ((lh << 4) ^ swz) >> 1;
  int koffB = ((64 | (lh << 4)) ^ swz) >> 1;
  u16* psw = ps + w * 1024 + l15 * 64;

  const int NC = SEQ / 64 / SPLIT;
  int kk0 = z * (SEQ / SPLIT);

#define STAGE_KV(buf, kk)                                                          \
  do {                                                                             \
    gll16(kws + ((size_t)(b * SEQ + (kk) + srow)) * 64 + ssw,                      \
          ksb + (buf) * 8192);                                                     \
    gll16(kws + ((size_t)(b * SEQ + (kk) + srow + 32)) * 64 + ssw,                 \
          ksb + (buf) * 8192 + 4096);                                              \
    gll16(vws + ((size_t)(b * 64 + srow)) * SEQ + (kk) + ssw,                      \
          vtb + (buf) * 8192);                                                     \
    gll16(vws + ((size_t)(b * 64 + srow + 32)) * SEQ + (kk) + ssw,                 \
          vtb + (buf) * 8192 + 4096);                                              \
  } while (0)

  STAGE_KV(0, kk0);
  __syncthreads();

  int cur = 0;
  for (int kc = 0; kc < NC; kc++) {
    int kk = kk0 + kc * 64;
    if (kc + 1 < NC) STAGE_KV(cur ^ 1, kk + 64);

    int4 mi[4];
#pragma unroll
    for (int nt = 0; nt < 4; nt++)
      mi[nt] = *(const int4*)(mrk + b * SEQ + kk + nt * 16 + lh * 4);

    const u16* kb = ks + cur * 4096;
    f32x4 sa[4];
#pragma unroll
    for (int nt = 0; nt < 4; nt++) {
      const u16* kr = kb + (nt * 16 + l15) * 64;
      bf16x8 k0 = *(const bf16x8*)(kr + koffA);
      bf16x8 k1 = *(const bf16x8*)(kr + koffB);
      f32x4 s = zero;
      s = __builtin_amdgcn_mfma_f32_16x16x32_bf16(k0, qb0, s, 0, 0, 0);
      s = __builtin_amdgcn_mfma_f32_16x16x32_bf16(k1, qb1, s, 0, 0, 0);
      sa[nt] = s;
    }

    const u16* vbb = vt + cur * 4096;
    bf16x8 vb[4][2];
#pragma unroll
    for (int ht = 0; ht < 4; ht++) {
      const u16* vr = vbb + (ht * 16 + l15) * 64;
      vb[ht][0] = *(const bf16x8*)(vr + koffA);
      vb[ht][1] = *(const bf16x8*)(vr + koffB);
    }

#pragma unroll
    for (int nt = 0; nt < 4; nt++) {
      sa[nt][0] = mi[nt].x ? sa[nt][0] : -INFINITY;
      sa[nt][1] = mi[nt].y ? sa[nt][1] : -INFINITY;
      sa[nt][2] = mi[nt].z ? sa[nt][2] : -INFINITY;
      sa[nt][3] = mi[nt].w ? sa[nt][3] : -INFINITY;
    }
    float t0 = fmaxf(fmaxf(sa[0][0], sa[0][1]), fmaxf(sa[0][2], sa[0][3]));
    float t1 = fmaxf(fmaxf(sa[1][0], sa[1][1]), fmaxf(sa[1][2], sa[1][3]));
    float t2 = fmaxf(fmaxf(sa[2][0], sa[2][1]), fmaxf(sa[2][2], sa[2][3]));
    float t3 = fmaxf(fmaxf(sa[3][0], sa[3][1]), fmaxf(sa[3][2], sa[3][3]));
    float tm = fmaxf(fmaxf(t0, t1), fmaxf(t2, t3));
    tm = fmaxf(tm, __shfl_xor(tm, 16));
    tm = fmaxf(tm, __shfl_xor(tm, 32));

    if (!__all(tm <= mrow + 8.0f)) {       // defer-max (T13)
      float nm = fmaxf(mrow, tm);
      float alpha = __expf(mrow - nm);
      mrow = nm;
      lrow *= alpha;
      float a0 = __shfl(alpha, lh * 4 + 0);
      float a1 = __shfl(alpha, lh * 4 + 1);
      float a2 = __shfl(alpha, lh * 4 + 2);
      float a3 = __shfl(alpha, lh * 4 + 3);
#pragma unroll
      for (int ht = 0; ht < 4; ht++) {
        o[ht][0] *= a0; o[ht][1] *= a1; o[ht][2] *= a2; o[ht][3] *= a3;
      }
    }

    float ts = 0.f;
#pragma unroll
    for (int nt = 0; nt < 4; nt++) {
#pragma unroll
      for (int r = 0; r < 4; r++) {
        float p = __expf(sa[nt][r] - mrow);
        sa[nt][r] = p;
        ts += p;
      }
    }
    ts += __shfl_xor(ts, 16);
    ts += __shfl_xor(ts, 32);
    lrow += ts;

#pragma unroll
    for (int nt = 0; nt < 4; nt++) {
      u32 plo = pk2(sa[nt][0], sa[nt][1]);
      u32 phi = pk2(sa[nt][2], sa[nt][3]);
      *(uint2*)&psw[(((nt * 32 + lh * 8) ^ swz) >> 1)] = make_uint2(plo, phi);
    }
    bf16x8 ap0 = *(const bf16x8*)(psw + koffA);
    bf16x8 ap1 = *(const bf16x8*)(psw + koffB);

#pragma unroll
    for (int ht = 0; ht < 4; ht++) {
      o[ht] = __builtin_amdgcn_mfma_f32_16x16x32_bf16(ap0, vb[ht][0], o[ht], 0, 0, 0);
      o[ht] = __builtin_amdgcn_mfma_f32_16x16x32_bf16(ap1, vb[ht][1], o[ht], 0, 0, 0);
    }
    __syncthreads();
    cur ^= 1;
  }
#undef STAGE_KV

#pragma unroll
  for (int r = 0; r < 4; r++) {
    int rr = q0 + w * 16 + lh * 4 + r;
    float* pob = po + ((size_t)z * NB * SEQ + (size_t)b * SEQ + rr) * 64;
#pragma unroll
    for (int ht = 0; ht < 4; ht++) pob[ht * 16 + l15] = o[ht][r];
  }
  if (lh == 0) {
    int rr = q0 + w * 16 + l15;
    pmp[(size_t)z * NB * SEQ + (size_t)b * SEQ + rr] = mrow;
    plp[(size_t)z * NB * SEQ + (size_t)b * SEQ + rr] = lrow;
  }
}

// ---------------- merge SPLIT partials -> fp32 out
__global__ __launch_bounds__(256) void merge_k(
    const float* __restrict__ po, const float* __restrict__ pmp,
    const float* __restrict__ plp, float* __restrict__ out) {
  int tid = threadIdx.x;
  int row = blockIdx.x * 32 + (tid >> 3);
  int c8 = (tid & 7) * 8;
  const int RT = NB * SEQ;

  float m[SPLIT], lv[SPLIT];
  float M = -INFINITY;
#pragma unroll
  for (int s = 0; s < SPLIT; s++) {
    m[s] = pmp[(size_t)s * RT + row];
    lv[s] = plp[(size_t)s * RT + row];
    M = fmaxf(M, m[s]);
  }
  float o8[8];
#pragma unroll
  for (int j = 0; j < 8; j++) o8[j] = 0.f;
  float L = 0.f;
  if (M != -INFINITY) {
#pragma unroll
    for (int s = 0; s < SPLIT; s++) {
      float ws = __expf(m[s] - M);
      L += ws * lv[s];
      const float* p = po + ((size_t)s * RT + row) * 64 + c8;
#pragma unroll
      for (int j = 0; j < 8; j++) o8[j] += ws * p[j];
    }
  }
  float inv = (L > 0.f) ? 1.0f / L : 0.f;
  float* op = out + (size_t)row * 64 + c8;
#pragma unroll
  for (int j = 0; j < 8; j++) op[j] = o8[j] * inv;
}

extern "C" void kernel_launch(void* const* d_in, const int* in_sizes, int n_in,
                              void* d_out, int out_size, void* d_ws, size_t ws_size,
                              hipStream_t stream) {
  const float* X   = (const float*)d_in[0];
  const int*   mrk = (const int*)d_in[1];
  const float* Wq  = (const float*)d_in[2];
  const float* Wk  = (const float*)d_in[3];
  const float* Wv  = (const float*)d_in[4];
  const float* Aq  = (const float*)d_in[5];
  const float* Bq  = (const float*)d_in[6];
  const float* Ak  = (const float*)d_in[7];
  const float* Bk  = (const float*)d_in[8];
  const float* Av  = (const float*)d_in[9];
  const float* Bv  = (const float*)d_in[10];

  u16* weff = (u16*)d_ws;
  u16* qws  = (u16*)((char*)d_ws + (512 << 10));
  u16* kws  = qws + (size_t)16384 * 64;
  u16* vws  = kws + (size_t)16384 * 64;
  float* po  = (float*)((char*)d_ws + ((size_t)6656 << 10));
  float* pmp = po + (size_t)SPLIT * 16384 * 64;
  float* plp = pmp + (size_t)SPLIT * 16384;

  // allow 120KB dynamic LDS for proj_k (idempotent, host-side, capture-safe)
  (void)hipFuncSetAttribute((const void*)proj_k,
                            hipFuncAttributeMaxDynamicSharedMemorySize, NBUF * BUFB);

  fold_k<<<192, 256, 0, stream>>>(Wq, Wk, Wv, Aq, Bq, Ak, Bk, Av, Bv, weff);
  proj_k<<<256, 512, NBUF * BUFB, stream>>>(X, weff, qws, kws, vws);
  attn_k<<<dim3(32, 8, SPLIT), 256, 0, stream>>>(qws, kws, vws, mrk, po, pmp, plp);
  merge_k<<<512, 256, 0, stream>>>(po, pmp, plp, (float*)d_out);
}